// Round 4
// baseline (10489.118 us; speedup 1.0000x reference)
//
#include <hip/hip_runtime.h>
#include <hip/hip_bf16.h>

#define BB 1024
#define NN 32
#define SUD 8
#define HD 64
#define NCD 4
#define ED 992      // NN*(NN-1)
#define NITER 5

// ---- fp32 weight workspace layout (element offsets into d_ws) ----
#define O_W2AT 0        // 18 x 64   W2aT[su][f] = W2a[f][su]
#define O_B2A  1152     // 64
#define O_W2B  1216     // 32 x 64   row-major as given
#define O_B2B  3264     // 32
#define O_W2CT 3296     // 32 x 8    W2cT[o][su] = W2c[su][o]
#define O_B2C  3552     // 8
#define O_WIHT 3560     // 10 x 192  WihT[k][o]
#define O_BIH  5480     // 192
#define O_WHHT 5672     // 64 x 192  WhhT[k][o]
#define O_BHH  17960    // 192
#define O_W4T  18152    // 64 x 8    W4T[k][su]
#define O_B4   18664    // 8
#define O_W3AT 18672    // 8 x 64    W3aT[k][f]
#define O_B3A  19184    // 64
#define O_W3BT 19248    // 64 x 32   W3bT[k][f]
#define O_B3B  21296    // 32
#define O_W3CT 21328    // 32 x 4    W3cT[k][c]
#define O_B3C  21456    // 4
#define O_W1AT 21460    // 3 x 8     W1aT[c][su]
#define O_B1A  21484    // 8
#define W_TOTAL 21492   // floats (= 85,968 bytes in d_ws)

typedef const float* fwp;

// Transpose all weights into the layouts the main kernel wants. One elem/thread.
__global__ void prep_weights(fwp W2a, fwp b2a, fwp W2b, fwp b2b, fwp W2c, fwp b2c,
                             fwp Wih, fwp bih, fwp Whh, fwp bhh,
                             fwp W3a, fwp b3a, fwp W3b, fwp b3b, fwp W3c, fwp b3c,
                             fwp W4, fwp b4, fwp W1a, fwp b1a, float* __restrict__ ws) {
  int idx = blockIdx.x * 256 + threadIdx.x;
  if (idx >= W_TOTAL) return;
  float v;
  if (idx < O_B2A)       { int p = idx;          int su = p / 64, f = p % 64;   v = W2a[f * 18 + su]; }
  else if (idx < O_W2B)  { v = b2a[idx - O_B2A]; }
  else if (idx < O_B2B)  { v = W2b[idx - O_W2B]; }
  else if (idx < O_W2CT) { v = b2b[idx - O_B2B]; }
  else if (idx < O_B2C)  { int p = idx - O_W2CT; int o = p / 8, su = p % 8;     v = W2c[su * 32 + o]; }
  else if (idx < O_WIHT) { v = b2c[idx - O_B2C]; }
  else if (idx < O_BIH)  { int p = idx - O_WIHT; int k = p / 192, o = p % 192;  v = Wih[o * 10 + k]; }
  else if (idx < O_WHHT) { v = bih[idx - O_BIH]; }
  else if (idx < O_BHH)  { int p = idx - O_WHHT; int k = p / 192, o = p % 192;  v = Whh[o * 64 + k]; }
  else if (idx < O_W4T)  { v = bhh[idx - O_BHH]; }
  else if (idx < O_B4)   { int p = idx - O_W4T;  int k = p / 8, su = p % 8;     v = W4[su * 64 + k]; }
  else if (idx < O_W3AT) { v = b4[idx - O_B4]; }
  else if (idx < O_B3A)  { int p = idx - O_W3AT; int k = p / 64, f = p % 64;    v = W3a[f * 8 + k]; }
  else if (idx < O_W3BT) { v = b3a[idx - O_B3A]; }
  else if (idx < O_B3B)  { int p = idx - O_W3BT; int k = p / 32, f = p % 32;    v = W3b[f * 64 + k]; }
  else if (idx < O_W3CT) { v = b3b[idx - O_B3B]; }
  else if (idx < O_B3C)  { int p = idx - O_W3CT; int k = p / 4, c = p % 4;      v = W3c[c * 32 + k]; }
  else if (idx < O_W1AT) { v = b3c[idx - O_B3C]; }
  else if (idx < O_B1A)  { int p = idx - O_W1AT; int c = p / 8, su = p % 8;     v = W1a[su * 3 + c]; }
  else                   { v = b1a[idx - O_B1A]; }
  ws[idx] = v;
}

// One block per batch sample. Entire 5-iteration recurrence lives in LDS/regs.
// Edge MLP is f-chunked (8 at a time) so the peak live set is ~70 VGPRs:
// the previous m1[64]-live-across-o-loop form spilled to scratch (2.4 GB HBM).
__global__ __launch_bounds__(256, 2) void gnn_fused(
    const float* __restrict__ read_gru_in,
    const float* __restrict__ gru_init,
    const float* __restrict__ feat,
    const float* __restrict__ edge_w,
    const float* __restrict__ noise_in,
    const float* __restrict__ xhat,
    const float* __restrict__ vep,
    const int* __restrict__ gnn_iter_p,
    const float* __restrict__ ws,
    float* __restrict__ out)
{
  __shared__ float  sA1[NN * 65];    // A1[n][f]   (pad 65: conflict-free)
  __shared__ float  sA2[NN * 65];    // A2[n][f]
  __shared__ float  sH [NN * 65];    // gru_hidden[n][k]
  __shared__ float  sNodes[NN * 9];  // init_nodes / read_gru [n][su]
  __shared__ float  sSum[NN * 8];    // sum_msgs[n][su]
  __shared__ float  sPart[256 * 9];  // per-thread partial sums (pad 9)
  __shared__ float  sEw[ED];         // per-sample edge weights
  __shared__ float2 sCW[64];         // (c1[f] = b2a+noise*W2a[:,17], wew[f] = W2a[:,16])
  __shared__ float  sX[NN];
  __shared__ float  sV[NN];

  const int b = blockIdx.x;
  const int t = threadIdx.x;

  // ---- load per-sample inputs ----
  float noi = noise_in[b];
  for (int e = t; e < ED; e += 256) sEw[e] = edge_w[b * ED + e];
  if (t < NN) { sX[t] = xhat[b * NN + t]; sV[t] = vep[b * NN + t]; }
  if (t < 64) {
    float c1 = ws[O_B2A + t] + noi * ws[O_W2AT + 17 * 64 + t];
    float wewf = ws[O_W2AT + 16 * 64 + t];
    sCW[t] = make_float2(c1, wewf);
  }
#pragma unroll
  for (int i = 0; i < 8; ++i) {
    int p = t + 256 * i;
    sH[(p >> 6) * 65 + (p & 63)] = gru_init[b * (NN * HD) + p];
  }
  const int git = gnn_iter_p[0];

  for (int it = 0; it < NITER; ++it) {
    // ---- init_nodes ----
    if (it == 0) {
      int n = t >> 3, su = t & 7;
      float acc;
      if (git == 0) {
        acc = ws[O_B1A + su];
#pragma unroll
        for (int c = 0; c < 3; ++c)
          acc += ws[O_W1AT + c * 8 + su] * feat[b * (NN * 3) + n * 3 + c];
      } else {
        acc = read_gru_in[b * (NN * SUD) + t];
      }
      sNodes[n * 9 + su] = acc;
    }
    __syncthreads();

    // ---- A1[n] = W2a[:,0:8] @ nodes[n],  A2[n] = W2a[:,8:16] @ nodes[n] ----
#pragma unroll
    for (int i = 0; i < 8; ++i) {
      int p = t + 256 * i;
      int n = p >> 6, f = p & 63;            // n is wave-uniform, f = lane
      float a1 = 0.f, a2 = 0.f;
#pragma unroll
      for (int su = 0; su < 8; ++su) {
        float nv = sNodes[n * 9 + su];       // LDS broadcast
        a1 += ws[O_W2AT + su * 64 + f] * nv; // coalesced fp32
        a2 += ws[O_W2AT + (8 + su) * 64 + f] * nv;
      }
      sA1[n * 65 + f] = a1;
      sA2[n * 65 + f] = a2;
    }
    __syncthreads();

    // ---- edge MLP, f-chunked (8): layer a assembly + layer b + fused layer c ----
    {
      int jj = t >> 3, ii = t & 7;           // dest node jj, sub-lane ii
      float msum[8];
#pragma unroll
      for (int s = 0; s < 8; ++s) msum[s] = 0.f;
      for (int k = ii; k < 31; k += 8) {
        int a = k + (k >= jj ? 1 : 0);       // temp_a index
        float ewv = sEw[jj * 31 + k];
        float acc[32];                        // layer-b pre-activations
#pragma unroll
        for (int o = 0; o < 32; ++o) acc[o] = ws[O_B2B + o];
#pragma unroll
        for (int fc = 0; fc < 64; fc += 8) {
          float m1c[8];
#pragma unroll
          for (int i = 0; i < 8; ++i) {
            int f = fc + i;
            float2 cw = sCW[f];              // broadcast b64
            float v = sA1[a * 65 + f] + sA2[jj * 65 + f] + cw.x + ewv * cw.y;
            m1c[i] = v > 0.f ? v : 0.f;
          }
#pragma unroll
          for (int o = 0; o < 32; ++o) {     // wave-uniform -> s_load_dwordx8
            const float* wrow = ws + O_W2B + o * 64 + fc;
#pragma unroll
            for (int i = 0; i < 8; ++i) acc[o] += wrow[i] * m1c[i];
          }
        }
        float m3[8];
#pragma unroll
        for (int s = 0; s < 8; ++s) m3[s] = ws[O_B2C + s];
#pragma unroll
        for (int o = 0; o < 32; ++o) {
          float a2v = acc[o] > 0.f ? acc[o] : 0.f;   // relu layer b
          const float* crow = ws + O_W2CT + o * 8;
#pragma unroll
          for (int s = 0; s < 8; ++s) m3[s] += crow[s] * a2v;  // fused layer c
        }
#pragma unroll
        for (int s = 0; s < 8; ++s) { float v = m3[s]; msum[s] += (v > 0.f ? v : 0.f); } // relu layer c
      }
#pragma unroll
      for (int s = 0; s < 8; ++s) sPart[t * 9 + s] = msum[s];
    }
    __syncthreads();

    // ---- reduce 8 partials per node -> sum_msgs ----
    {
      int n = t >> 3, su = t & 7;
      float acc = 0.f;
#pragma unroll
      for (int i = 0; i < 8; ++i) acc += sPart[(n * 8 + i) * 9 + su];
      sSum[n * 8 + su] = acc;
    }
    __syncthreads();

    // ---- GRU: lane owns gate-column oo for 8 nodes ----
    {
      int oo = t & 63, wq = t >> 6;
      float ar[8], az[8], inx[8], hn[8];
      {
        float br  = ws[O_BIH + oo]        + ws[O_BHH + oo];
        float bz  = ws[O_BIH + 64 + oo]   + ws[O_BHH + 64 + oo];
        float bni = ws[O_BIH + 128 + oo];
        float bnh = ws[O_BHH + 128 + oo];
#pragma unroll
        for (int j = 0; j < 8; ++j) { ar[j] = br; az[j] = bz; inx[j] = bni; hn[j] = bnh; }
      }
#pragma unroll
      for (int k = 0; k < 8; ++k) {          // gi over sum_msgs
        float wr = ws[O_WIHT + k * 192 + oo];
        float wz = ws[O_WIHT + k * 192 + 64 + oo];
        float wn = ws[O_WIHT + k * 192 + 128 + oo];
#pragma unroll
        for (int j = 0; j < 8; ++j) {
          float g = sSum[(wq + 4 * j) * 8 + k];
          ar[j] += wr * g; az[j] += wz * g; inx[j] += wn * g;
        }
      }
      {                                      // gi over x_hat (k=8) and var (k=9)
        float wr = ws[O_WIHT + 8 * 192 + oo];
        float wz = ws[O_WIHT + 8 * 192 + 64 + oo];
        float wn = ws[O_WIHT + 8 * 192 + 128 + oo];
#pragma unroll
        for (int j = 0; j < 8; ++j) {
          float g = sX[wq + 4 * j];
          ar[j] += wr * g; az[j] += wz * g; inx[j] += wn * g;
        }
        wr = ws[O_WIHT + 9 * 192 + oo];
        wz = ws[O_WIHT + 9 * 192 + 64 + oo];
        wn = ws[O_WIHT + 9 * 192 + 128 + oo];
#pragma unroll
        for (int j = 0; j < 8; ++j) {
          float g = sV[wq + 4 * j];
          ar[j] += wr * g; az[j] += wz * g; inx[j] += wn * g;
        }
      }
#pragma unroll 4
      for (int k = 0; k < 64; ++k) {         // gh over hidden
        float wr = ws[O_WHHT + k * 192 + oo];
        float wz = ws[O_WHHT + k * 192 + 64 + oo];
        float wn = ws[O_WHHT + k * 192 + 128 + oo];
#pragma unroll
        for (int j = 0; j < 8; ++j) {
          float hk = sH[(wq + 4 * j) * 65 + k];  // broadcast
          ar[j] += wr * hk; az[j] += wz * hk; hn[j] += wn * hk;
        }
      }
      float hnew[8];
#pragma unroll
      for (int j = 0; j < 8; ++j) {
        int n = wq + 4 * j;
        float r = 1.f / (1.f + __expf(-ar[j]));
        float z = 1.f / (1.f + __expf(-az[j]));
        float cd = inx[j] + r * hn[j];
        float e2 = __expf(2.f * cd);
        float th = 1.f - 2.f / (e2 + 1.f);   // tanh(cd)
        hnew[j] = (1.f - z) * th + z * sH[n * 65 + oo];
      }
      __syncthreads();                        // all old-h reads done
#pragma unroll
      for (int j = 0; j < 8; ++j) sH[(wq + 4 * j) * 65 + oo] = hnew[j];
    }
    __syncthreads();

    // ---- read_gru = W4 @ h + b4 -> sNodes (next iter's init_nodes) ----
    {
      int n = t >> 3, su = t & 7;
      float c0 = 0.f, c1v = 0.f, c2 = 0.f, c3 = 0.f;
#pragma unroll
      for (int k = 0; k < 64; k += 4) {
        c0  += ws[O_W4T + (k + 0) * 8 + su] * sH[n * 65 + k + 0];
        c1v += ws[O_W4T + (k + 1) * 8 + su] * sH[n * 65 + k + 1];
        c2  += ws[O_W4T + (k + 2) * 8 + su] * sH[n * 65 + k + 2];
        c3  += ws[O_W4T + (k + 3) * 8 + su] * sH[n * 65 + k + 3];
      }
      sNodes[n * 9 + su] = ws[O_B4 + su] + ((c0 + c1v) + (c2 + c3));
    }
    __syncthreads();
  } // iterations

  // ---- head: q1 = read @ W3aT + b3a (32x64) -> reuse sA1 ----
#pragma unroll
  for (int i = 0; i < 8; ++i) {
    int p = t + 256 * i;
    int n = p >> 6, f = p & 63;
    float acc = ws[O_B3A + f];
#pragma unroll
    for (int k = 0; k < 8; ++k) acc += ws[O_W3AT + k * 64 + f] * sNodes[n * 9 + k];
    sA1[n * 65 + f] = acc;
  }
  __syncthreads();
  // q2 (32x32) -> reuse sA2 at stride 33
#pragma unroll
  for (int i = 0; i < 4; ++i) {
    int p = t + 256 * i;
    int n = p >> 5, f = p & 31;
    float c0 = 0.f, c1v = 0.f, c2 = 0.f, c3 = 0.f;
#pragma unroll
    for (int k = 0; k < 64; k += 4) {
      c0  += ws[O_W3BT + (k + 0) * 32 + f] * sA1[n * 65 + k + 0];
      c1v += ws[O_W3BT + (k + 1) * 32 + f] * sA1[n * 65 + k + 1];
      c2  += ws[O_W3BT + (k + 2) * 32 + f] * sA1[n * 65 + k + 2];
      c3  += ws[O_W3BT + (k + 3) * 32 + f] * sA1[n * 65 + k + 3];
    }
    sA2[n * 33 + f] = ws[O_B3B + f] + ((c0 + c1v) + (c2 + c3));
  }
  __syncthreads();
  // p_y_x (32x4) + store
  if (t < 128) {
    int n = t >> 2, c = t & 3;
    float acc = ws[O_B3C + c];
#pragma unroll
    for (int k = 0; k < 32; ++k) acc += ws[O_W3CT + k * 4 + c] * sA2[n * 33 + k];
    out[b * (NN * NCD) + t] = acc;
  }
  // read_gru out
  out[BB * NN * NCD + b * (NN * SUD) + t] = sNodes[(t >> 3) * 9 + (t & 7)];
  // gru_hidden out
#pragma unroll
  for (int i = 0; i < 8; ++i) {
    int p = t + 256 * i;
    out[BB * NN * NCD + BB * NN * SUD + b * (NN * HD) + p] =
        sH[(p >> 6) * 65 + (p & 63)];
  }
}

extern "C" void kernel_launch(void* const* d_in, const int* in_sizes, int n_in,
                              void* d_out, int out_size, void* d_ws, size_t ws_size,
                              hipStream_t stream) {
  typedef const float* F32;
  F32 read_gru = (F32)d_in[0];
  F32 gru_init = (F32)d_in[1];
  F32 feat     = (F32)d_in[2];
  F32 edge_w   = (F32)d_in[3];
  F32 noise    = (F32)d_in[4];
  F32 xh       = (F32)d_in[5];
  F32 vp       = (F32)d_in[6];
  F32 W1a = (F32)d_in[7];  F32 b1a = (F32)d_in[8];
  F32 W2a = (F32)d_in[9];  F32 b2a = (F32)d_in[10];
  F32 W2b = (F32)d_in[11]; F32 b2b = (F32)d_in[12];
  F32 W2c = (F32)d_in[13]; F32 b2c = (F32)d_in[14];
  F32 Wih = (F32)d_in[15]; F32 bih = (F32)d_in[16];
  F32 Whh = (F32)d_in[17]; F32 bhh = (F32)d_in[18];
  F32 W3a = (F32)d_in[19]; F32 b3a = (F32)d_in[20];
  F32 W3b = (F32)d_in[21]; F32 b3b = (F32)d_in[22];
  F32 W3c = (F32)d_in[23]; F32 b3c = (F32)d_in[24];
  F32 W4  = (F32)d_in[25]; F32 b4  = (F32)d_in[26];
  const int* git = (const int*)d_in[27];
  float* ws = (float*)d_ws;   // needs 85,968 B

  prep_weights<<<(W_TOTAL + 255) / 256, 256, 0, stream>>>(
      W2a, b2a, W2b, b2b, W2c, b2c, Wih, bih, Whh, bhh,
      W3a, b3a, W3b, b3b, W3c, b3c, W4, b4, W1a, b1a, ws);

  gnn_fused<<<BB, 256, 0, stream>>>(read_gru, gru_init, feat, edge_w, noise,
                                    xh, vp, git, ws, (float*)d_out);
}

// Round 5
// 789.008 us; speedup vs baseline: 13.2941x; 13.2941x over previous
//
#include <hip/hip_runtime.h>
#include <hip/hip_bf16.h>

#define BB 1024
#define NN 32
#define SUD 8
#define HD 64
#define NCD 4
#define ED 992      // NN*(NN-1)
#define NITER 5

// ---- fp32 weight workspace layout (element offsets into d_ws) ----
#define O_W2AT 0        // 18 x 64   W2aT[su][f] = W2a[f][su]
#define O_B2A  1152     // 64
#define O_W2B  1216     // 32 x 64   row-major as given
#define O_B2B  3264     // 32
#define O_W2CT 3296     // 32 x 8    (unused by main now, kept for layout stability)
#define O_B2C  3552     // 8
#define O_WIHT 3560     // 10 x 192  WihT[k][o]
#define O_BIH  5480     // 192
#define O_WHHT 5672     // 64 x 192  WhhT[k][o]
#define O_BHH  17960    // 192
#define O_W4T  18152    // 64 x 8    W4T[k][su]
#define O_B4   18664    // 8
#define O_W3AT 18672    // 8 x 64    W3aT[k][f]
#define O_B3A  19184    // 64
#define O_W3BT 19248    // 64 x 32   W3bT[k][f]
#define O_B3B  21296    // 32
#define O_W3CT 21328    // 32 x 4    W3cT[k][c]
#define O_B3C  21456    // 4
#define O_W1AT 21460    // 3 x 8     W1aT[c][su]
#define O_B1A  21484    // 8
#define W_TOTAL 21492   // floats

// ---- bf16 MFMA fragment region, at byte offset W_TOTAL*4 ----
// e in [0,2048):    fragB2 hi : ((h*2+s)*64+L)*8+j = W2b[h*16+(L&15)][s*32+((L>>4)&3)*8+j]
// lo twin stored at [2048,4096). e in [4096,4608): fragC: (L*8+j) = (L&15)<8 ? W2c[L&15][(L>>4)*8+j] : 0
#define FRAG_B2_HI 0
#define FRAG_B2_LO 2048
#define FRAG_C     4096
#define W_EXT (W_TOTAL + 2560)   // prep thread count

typedef const float* fwp;
typedef __attribute__((ext_vector_type(8))) short short8;
typedef __attribute__((ext_vector_type(4))) float float4v;

__device__ __forceinline__ short bf16r(float x) {
  __hip_bfloat16 h = __float2bfloat16(x);
  return __builtin_bit_cast(short, h);
}
__device__ __forceinline__ float bf16tof(short s) {
  __hip_bfloat16 h = __builtin_bit_cast(__hip_bfloat16, s);
  return __bfloat162float(h);
}

__global__ void prep_weights(fwp W2a, fwp b2a, fwp W2b, fwp b2b, fwp W2c, fwp b2c,
                             fwp Wih, fwp bih, fwp Whh, fwp bhh,
                             fwp W3a, fwp b3a, fwp W3b, fwp b3b, fwp W3c, fwp b3c,
                             fwp W4, fwp b4, fwp W1a, fwp b1a, float* __restrict__ ws) {
  int idx = blockIdx.x * 256 + threadIdx.x;
  if (idx >= W_EXT) return;
  if (idx >= W_TOTAL) {
    __hip_bfloat16* wb = (__hip_bfloat16*)(ws + W_TOTAL);
    int e = idx - W_TOTAL;
    if (e < 2048) {
      int j = e & 7, L = (e >> 3) & 63, hs = e >> 9;
      int h = hs >> 1, s = hs & 1;
      float v = W2b[(h * 16 + (L & 15)) * 64 + s * 32 + ((L >> 4) & 3) * 8 + j];
      float hi = __bfloat162float(__float2bfloat16(v));
      wb[FRAG_B2_HI + e] = __float2bfloat16(v);
      wb[FRAG_B2_LO + e] = __float2bfloat16(v - hi);
    } else {
      int e2 = e - 2048;               // [0,512)
      int j = e2 & 7, L = (e2 >> 3) & 63;
      int su = L & 15, q = L >> 4;
      float v = (su < 8) ? W2c[su * 32 + q * 8 + j] : 0.f;
      wb[FRAG_C + e2] = __float2bfloat16(v);
    }
    return;
  }
  float v;
  if (idx < O_B2A)       { int p = idx;          int su = p / 64, f = p % 64;   v = W2a[f * 18 + su]; }
  else if (idx < O_W2B)  { v = b2a[idx - O_B2A]; }
  else if (idx < O_B2B)  { v = W2b[idx - O_W2B]; }
  else if (idx < O_W2CT) { v = b2b[idx - O_B2B]; }
  else if (idx < O_B2C)  { int p = idx - O_W2CT; int o = p / 8, su = p % 8;     v = W2c[su * 32 + o]; }
  else if (idx < O_WIHT) { v = b2c[idx - O_B2C]; }
  else if (idx < O_BIH)  { int p = idx - O_WIHT; int k = p / 192, o = p % 192;  v = Wih[o * 10 + k]; }
  else if (idx < O_WHHT) { v = bih[idx - O_BIH]; }
  else if (idx < O_BHH)  { int p = idx - O_WHHT; int k = p / 192, o = p % 192;  v = Whh[o * 64 + k]; }
  else if (idx < O_W4T)  { v = bhh[idx - O_BHH]; }
  else if (idx < O_B4)   { int p = idx - O_W4T;  int k = p / 8, su = p % 8;     v = W4[su * 64 + k]; }
  else if (idx < O_W3AT) { v = b4[idx - O_B4]; }
  else if (idx < O_B3A)  { int p = idx - O_W3AT; int k = p / 64, f = p % 64;    v = W3a[f * 8 + k]; }
  else if (idx < O_W3BT) { v = b3a[idx - O_B3A]; }
  else if (idx < O_B3B)  { int p = idx - O_W3BT; int k = p / 32, f = p % 32;    v = W3b[f * 64 + k]; }
  else if (idx < O_W3CT) { v = b3b[idx - O_B3B]; }
  else if (idx < O_B3C)  { int p = idx - O_W3CT; int k = p / 4, c = p % 4;      v = W3c[c * 32 + k]; }
  else if (idx < O_W1AT) { v = b3c[idx - O_B3C]; }
  else if (idx < O_B1A)  { int p = idx - O_W1AT; int c = p / 8, su = p % 8;     v = W1a[su * 3 + c]; }
  else                   { v = b1a[idx - O_B1A]; }
  ws[idx] = v;
}

// Layer-b K-step: assemble 8 m1 values (k = KOFF..KOFF+7 for this lane's quad),
// relu, bf16 hi/lo split, 3-product MFMA into both N-half accumulators.
#define DO_STEP(KOFF, Y0, Y1, C0, C1, W0, W1, FH0, FL0, FH1, FL1)              \
  {                                                                            \
    float4v x0 = *(const float4v*)&sA1[a * 68 + (KOFF)];                       \
    float4v x1 = *(const float4v*)&sA1[a * 68 + (KOFF) + 4];                   \
    float t0 = fmaxf(x0.x + Y0.x + C0.x + ewv * W0.x, 0.f);                    \
    float t1 = fmaxf(x0.y + Y0.y + C0.y + ewv * W0.y, 0.f);                    \
    float t2 = fmaxf(x0.z + Y0.z + C0.z + ewv * W0.z, 0.f);                    \
    float t3 = fmaxf(x0.w + Y0.w + C0.w + ewv * W0.w, 0.f);                    \
    float t4 = fmaxf(x1.x + Y1.x + C1.x + ewv * W1.x, 0.f);                    \
    float t5 = fmaxf(x1.y + Y1.y + C1.y + ewv * W1.y, 0.f);                    \
    float t6 = fmaxf(x1.z + Y1.z + C1.z + ewv * W1.z, 0.f);                    \
    float t7 = fmaxf(x1.w + Y1.w + C1.w + ewv * W1.w, 0.f);                    \
    short8 ahi, alo;                                                           \
    ahi[0] = bf16r(t0); ahi[1] = bf16r(t1); ahi[2] = bf16r(t2);                \
    ahi[3] = bf16r(t3); ahi[4] = bf16r(t4); ahi[5] = bf16r(t5);                \
    ahi[6] = bf16r(t6); ahi[7] = bf16r(t7);                                    \
    alo[0] = bf16r(t0 - bf16tof(ahi[0])); alo[1] = bf16r(t1 - bf16tof(ahi[1]));\
    alo[2] = bf16r(t2 - bf16tof(ahi[2])); alo[3] = bf16r(t3 - bf16tof(ahi[3]));\
    alo[4] = bf16r(t4 - bf16tof(ahi[4])); alo[5] = bf16r(t5 - bf16tof(ahi[5]));\
    alo[6] = bf16r(t6 - bf16tof(ahi[6])); alo[7] = bf16r(t7 - bf16tof(ahi[7]));\
    accb0 = __builtin_amdgcn_mfma_f32_16x16x32_bf16(ahi, FH0, accb0, 0, 0, 0); \
    accb0 = __builtin_amdgcn_mfma_f32_16x16x32_bf16(alo, FH0, accb0, 0, 0, 0); \
    accb0 = __builtin_amdgcn_mfma_f32_16x16x32_bf16(ahi, FL0, accb0, 0, 0, 0); \
    accb1 = __builtin_amdgcn_mfma_f32_16x16x32_bf16(ahi, FH1, accb1, 0, 0, 0); \
    accb1 = __builtin_amdgcn_mfma_f32_16x16x32_bf16(alo, FH1, accb1, 0, 0, 0); \
    accb1 = __builtin_amdgcn_mfma_f32_16x16x32_bf16(ahi, FL1, accb1, 0, 0, 0); \
  }

__global__ __launch_bounds__(256, 2) void gnn_fused(
    const float* __restrict__ read_gru_in,
    const float* __restrict__ gru_init,
    const float* __restrict__ feat,
    const float* __restrict__ edge_w,
    const float* __restrict__ noise_in,
    const float* __restrict__ xhat,
    const float* __restrict__ vep,
    const int* __restrict__ gnn_iter_p,
    const float* __restrict__ ws,
    float* __restrict__ out)
{
  __shared__ __attribute__((aligned(16))) float sA1[NN * 68];
  __shared__ __attribute__((aligned(16))) float sA2[NN * 68];
  __shared__ __attribute__((aligned(16))) float sH [NN * 68];
  __shared__ __attribute__((aligned(16))) float sC1[64];
  __shared__ __attribute__((aligned(16))) float sWew[64];
  __shared__ __attribute__((aligned(16))) __hip_bfloat16 sM2[4 * 16 * 40]; // wave-private 16x40 tiles
  __shared__ float sNodes[NN * 9];
  __shared__ float sSum[NN * 8];
  __shared__ float sEw[ED];
  __shared__ float sX[NN];
  __shared__ float sV[NN];

  const int b = blockIdx.x;
  const int t = threadIdx.x;
  const int lane = t & 63;
  const int wv = t >> 6;          // wave id 0..3
  const int quad = lane >> 4;     // 0..3
  const int lm = lane & 15;

  // ---- persistent MFMA B fragments (global, written by prep) ----
  const __hip_bfloat16* wb = (const __hip_bfloat16*)(ws + W_TOTAL);
  short8 fbh00 = *(const short8*)(wb + FRAG_B2_HI + ((0 * 64 + lane) * 8));
  short8 fbh01 = *(const short8*)(wb + FRAG_B2_HI + ((1 * 64 + lane) * 8));
  short8 fbh10 = *(const short8*)(wb + FRAG_B2_HI + ((2 * 64 + lane) * 8));
  short8 fbh11 = *(const short8*)(wb + FRAG_B2_HI + ((3 * 64 + lane) * 8));
  short8 fbl00 = *(const short8*)(wb + FRAG_B2_LO + ((0 * 64 + lane) * 8));
  short8 fbl01 = *(const short8*)(wb + FRAG_B2_LO + ((1 * 64 + lane) * 8));
  short8 fbl10 = *(const short8*)(wb + FRAG_B2_LO + ((2 * 64 + lane) * 8));
  short8 fbl11 = *(const short8*)(wb + FRAG_B2_LO + ((3 * 64 + lane) * 8));
  short8 fcf   = *(const short8*)(wb + FRAG_C + lane * 8);
  const float b2b0 = ws[O_B2B + lm];
  const float b2b1 = ws[O_B2B + 16 + lm];
  const float b2cl = ws[O_B2C + lm];   // garbage for lm>=8, discarded at write

  // ---- per-sample inputs ----
  float noi = noise_in[b];
  for (int e = t; e < ED; e += 256) sEw[e] = edge_w[b * ED + e];
  if (t < NN) { sX[t] = xhat[b * NN + t]; sV[t] = vep[b * NN + t]; }
  if (t < 64) {
    sC1[t]  = ws[O_B2A + t] + noi * ws[O_W2AT + 17 * 64 + t];
    sWew[t] = ws[O_W2AT + 16 * 64 + t];
  }
#pragma unroll
  for (int i = 0; i < 8; ++i) {
    int p = t + 256 * i;
    sH[(p >> 6) * 68 + (p & 63)] = gru_init[b * (NN * HD) + p];
  }
  const int git = gnn_iter_p[0];

  for (int it = 0; it < NITER; ++it) {
    // ---- init_nodes ----
    if (it == 0) {
      int n = t >> 3, su = t & 7;
      float acc;
      if (git == 0) {
        acc = ws[O_B1A + su];
#pragma unroll
        for (int c = 0; c < 3; ++c)
          acc += ws[O_W1AT + c * 8 + su] * feat[b * (NN * 3) + n * 3 + c];
      } else {
        acc = read_gru_in[b * (NN * SUD) + t];
      }
      sNodes[n * 9 + su] = acc;
    }
    __syncthreads();

    // ---- A1[n] = W2a[:,0:8] @ nodes[n],  A2[n] = W2a[:,8:16] @ nodes[n] ----
#pragma unroll
    for (int i = 0; i < 8; ++i) {
      int p = t + 256 * i;
      int n = p >> 6, f = p & 63;
      float a1 = 0.f, a2 = 0.f;
#pragma unroll
      for (int su = 0; su < 8; ++su) {
        float nv = sNodes[n * 9 + su];
        a1 += ws[O_W2AT + su * 64 + f] * nv;
        a2 += ws[O_W2AT + (8 + su) * 64 + f] * nv;
      }
      sA1[n * 68 + f] = a1;
      sA2[n * 68 + f] = a2;
    }
    __syncthreads();

    // ---- edge MLP via MFMA: per wave, 8 nodes; per node 2 M-tiles of 16 edges ----
    {
      __hip_bfloat16* m2w = sM2 + wv * (16 * 40);
      const int kq0 = quad * 8, kq1 = 32 + quad * 8;
      float4v c1A = *(const float4v*)&sC1[kq0];
      float4v c1B = *(const float4v*)&sC1[kq0 + 4];
      float4v c1C = *(const float4v*)&sC1[kq1];
      float4v c1D = *(const float4v*)&sC1[kq1 + 4];
      float4v wwA = *(const float4v*)&sWew[kq0];
      float4v wwB = *(const float4v*)&sWew[kq0 + 4];
      float4v wwC = *(const float4v*)&sWew[kq1];
      float4v wwD = *(const float4v*)&sWew[kq1 + 4];
      for (int ni = 0; ni < 8; ++ni) {
        const int jj = wv * 8 + ni;
        float4v yA = *(const float4v*)&sA2[jj * 68 + kq0];
        float4v yB = *(const float4v*)&sA2[jj * 68 + kq0 + 4];
        float4v yC = *(const float4v*)&sA2[jj * 68 + kq1];
        float4v yD = *(const float4v*)&sA2[jj * 68 + kq1 + 4];
        float psum = 0.f;
#pragma unroll
        for (int tile = 0; tile < 2; ++tile) {
          int kk = tile * 16 + lm;
          int kk2 = (kk < 31) ? kk : 0;              // pad slot aliases edge 0 (masked)
          int a = kk2 + (kk2 >= jj ? 1 : 0);
          float ewv = (kk < 31) ? sEw[jj * 31 + kk] : 0.f;
          float4v accb0 = {0.f, 0.f, 0.f, 0.f};
          float4v accb1 = {0.f, 0.f, 0.f, 0.f};
          DO_STEP(kq0, yA, yB, c1A, c1B, wwA, wwB, fbh00, fbl00, fbh10, fbl10);
          DO_STEP(kq1, yC, yD, c1C, c1D, wwC, wwD, fbh01, fbl01, fbh11, fbl11);
          // m2 = relu(acc + b2b) -> wave-private LDS tile (bf16), C-layout -> [row][col]
#pragma unroll
          for (int r = 0; r < 4; ++r) {
            float m20 = fmaxf(accb0[r] + b2b0, 0.f);
            float m21 = fmaxf(accb1[r] + b2b1, 0.f);
            m2w[(quad * 4 + r) * 40 + lm]      = __float2bfloat16(m20);
            m2w[(quad * 4 + r) * 40 + 16 + lm] = __float2bfloat16(m21);
          }
          __asm__ __volatile__("" ::: "memory");  // keep DS program order (in-order per wave)
          // layer c: A[m=lm][k=quad*8+j] from tile, one MFMA (K=32, N=16 padded)
          short8 ac = *(const short8*)(m2w + lm * 40 + quad * 8);
          float4v c3 = {0.f, 0.f, 0.f, 0.f};
          c3 = __builtin_amdgcn_mfma_f32_16x16x32_bf16(ac, fcf, c3, 0, 0, 0);
#pragma unroll
          for (int r = 0; r < 4; ++r) {
            float v = fmaxf(c3[r] + b2cl, 0.f);
            if (tile == 1 && r == 3) v = (quad == 3) ? 0.f : v;  // mask pad slot 31
            psum += v;
          }
          __asm__ __volatile__("" ::: "memory");  // reads done before next tile's writes
        }
        psum += __shfl_xor(psum, 16);
        psum += __shfl_xor(psum, 32);
        if (lane < 8) sSum[jj * 8 + lane] = psum;
      }
    }
    __syncthreads();

    // ---- GRU: lane owns gate-column oo for 8 nodes (unchanged from R3) ----
    {
      int oo = t & 63, wq = t >> 6;
      float ar[8], az[8], inx[8], hn[8];
      {
        float br  = ws[O_BIH + oo]        + ws[O_BHH + oo];
        float bz  = ws[O_BIH + 64 + oo]   + ws[O_BHH + 64 + oo];
        float bni = ws[O_BIH + 128 + oo];
        float bnh = ws[O_BHH + 128 + oo];
#pragma unroll
        for (int j = 0; j < 8; ++j) { ar[j] = br; az[j] = bz; inx[j] = bni; hn[j] = bnh; }
      }
#pragma unroll
      for (int k = 0; k < 8; ++k) {
        float wr = ws[O_WIHT + k * 192 + oo];
        float wz = ws[O_WIHT + k * 192 + 64 + oo];
        float wn = ws[O_WIHT + k * 192 + 128 + oo];
#pragma unroll
        for (int j = 0; j < 8; ++j) {
          float g = sSum[(wq + 4 * j) * 8 + k];
          ar[j] += wr * g; az[j] += wz * g; inx[j] += wn * g;
        }
      }
      {
        float wr = ws[O_WIHT + 8 * 192 + oo];
        float wz = ws[O_WIHT + 8 * 192 + 64 + oo];
        float wn = ws[O_WIHT + 8 * 192 + 128 + oo];
#pragma unroll
        for (int j = 0; j < 8; ++j) {
          float g = sX[wq + 4 * j];
          ar[j] += wr * g; az[j] += wz * g; inx[j] += wn * g;
        }
        wr = ws[O_WIHT + 9 * 192 + oo];
        wz = ws[O_WIHT + 9 * 192 + 64 + oo];
        wn = ws[O_WIHT + 9 * 192 + 128 + oo];
#pragma unroll
        for (int j = 0; j < 8; ++j) {
          float g = sV[wq + 4 * j];
          ar[j] += wr * g; az[j] += wz * g; inx[j] += wn * g;
        }
      }
#pragma unroll 4
      for (int k = 0; k < 64; ++k) {
        float wr = ws[O_WHHT + k * 192 + oo];
        float wz = ws[O_WHHT + k * 192 + 64 + oo];
        float wn = ws[O_WHHT + k * 192 + 128 + oo];
#pragma unroll
        for (int j = 0; j < 8; ++j) {
          float hk = sH[(wq + 4 * j) * 68 + k];
          ar[j] += wr * hk; az[j] += wz * hk; hn[j] += wn * hk;
        }
      }
      float hnew[8];
#pragma unroll
      for (int j = 0; j < 8; ++j) {
        int n = wq + 4 * j;
        float r = 1.f / (1.f + __expf(-ar[j]));
        float z = 1.f / (1.f + __expf(-az[j]));
        float cd = inx[j] + r * hn[j];
        float e2 = __expf(2.f * cd);
        float th = 1.f - 2.f / (e2 + 1.f);
        hnew[j] = (1.f - z) * th + z * sH[n * 68 + oo];
      }
      __syncthreads();
#pragma unroll
      for (int j = 0; j < 8; ++j) sH[(wq + 4 * j) * 68 + oo] = hnew[j];
    }
    __syncthreads();

    // ---- read_gru = W4 @ h + b4 -> sNodes ----
    {
      int n = t >> 3, su = t & 7;
      float c0 = 0.f, c1v = 0.f, c2 = 0.f, c3v = 0.f;
#pragma unroll
      for (int k = 0; k < 64; k += 4) {
        c0  += ws[O_W4T + (k + 0) * 8 + su] * sH[n * 68 + k + 0];
        c1v += ws[O_W4T + (k + 1) * 8 + su] * sH[n * 68 + k + 1];
        c2  += ws[O_W4T + (k + 2) * 8 + su] * sH[n * 68 + k + 2];
        c3v += ws[O_W4T + (k + 3) * 8 + su] * sH[n * 68 + k + 3];
      }
      sNodes[n * 9 + su] = ws[O_B4 + su] + ((c0 + c1v) + (c2 + c3v));
    }
    __syncthreads();
  } // iterations

  // ---- head ----
#pragma unroll
  for (int i = 0; i < 8; ++i) {
    int p = t + 256 * i;
    int n = p >> 6, f = p & 63;
    float acc = ws[O_B3A + f];
#pragma unroll
    for (int k = 0; k < 8; ++k) acc += ws[O_W3AT + k * 64 + f] * sNodes[n * 9 + k];
    sA1[n * 68 + f] = acc;
  }
  __syncthreads();
#pragma unroll
  for (int i = 0; i < 4; ++i) {
    int p = t + 256 * i;
    int n = p >> 5, f = p & 31;
    float c0 = 0.f, c1v = 0.f, c2 = 0.f, c3v = 0.f;
#pragma unroll
    for (int k = 0; k < 64; k += 4) {
      c0  += ws[O_W3BT + (k + 0) * 32 + f] * sA1[n * 68 + k + 0];
      c1v += ws[O_W3BT + (k + 1) * 32 + f] * sA1[n * 68 + k + 1];
      c2  += ws[O_W3BT + (k + 2) * 32 + f] * sA1[n * 68 + k + 2];
      c3v += ws[O_W3BT + (k + 3) * 32 + f] * sA1[n * 68 + k + 3];
    }
    sA2[n * 33 + f] = ws[O_B3B + f] + ((c0 + c1v) + (c2 + c3v));
  }
  __syncthreads();
  if (t < 128) {
    int n = t >> 2, c = t & 3;
    float acc = ws[O_B3C + c];
#pragma unroll
    for (int k = 0; k < 32; ++k) acc += ws[O_W3CT + k * 4 + c] * sA2[n * 33 + k];
    out[b * (NN * NCD) + t] = acc;
  }
  out[BB * NN * NCD + b * (NN * SUD) + t] = sNodes[(t >> 3) * 9 + (t & 7)];
#pragma unroll
  for (int i = 0; i < 8; ++i) {
    int p = t + 256 * i;
    out[BB * NN * NCD + BB * NN * SUD + b * (NN * HD) + p] =
        sH[(p >> 6) * 68 + (p & 63)];
  }
}

extern "C" void kernel_launch(void* const* d_in, const int* in_sizes, int n_in,
                              void* d_out, int out_size, void* d_ws, size_t ws_size,
                              hipStream_t stream) {
  typedef const float* F32;
  F32 read_gru = (F32)d_in[0];
  F32 gru_init = (F32)d_in[1];
  F32 feat     = (F32)d_in[2];
  F32 edge_w   = (F32)d_in[3];
  F32 noise    = (F32)d_in[4];
  F32 xh       = (F32)d_in[5];
  F32 vp       = (F32)d_in[6];
  F32 W1a = (F32)d_in[7];  F32 b1a = (F32)d_in[8];
  F32 W2a = (F32)d_in[9];  F32 b2a = (F32)d_in[10];
  F32 W2b = (F32)d_in[11]; F32 b2b = (F32)d_in[12];
  F32 W2c = (F32)d_in[13]; F32 b2c = (F32)d_in[14];
  F32 Wih = (F32)d_in[15]; F32 bih = (F32)d_in[16];
  F32 Whh = (F32)d_in[17]; F32 bhh = (F32)d_in[18];
  F32 W3a = (F32)d_in[19]; F32 b3a = (F32)d_in[20];
  F32 W3b = (F32)d_in[21]; F32 b3b = (F32)d_in[22];
  F32 W3c = (F32)d_in[23]; F32 b3c = (F32)d_in[24];
  F32 W4  = (F32)d_in[25]; F32 b4  = (F32)d_in[26];
  const int* git = (const int*)d_in[27];
  float* ws = (float*)d_ws;   // needs 95,184 B

  prep_weights<<<(W_EXT + 255) / 256, 256, 0, stream>>>(
      W2a, b2a, W2b, b2b, W2c, b2c, Wih, bih, Whh, bhh,
      W3a, b3a, W3b, b3b, W3c, b3c, W4, b4, W1a, b1a, ws);

  gnn_fused<<<BB, 256, 0, stream>>>(read_gru, gru_init, feat, edge_w, noise,
                                    xh, vp, git, ws, (float*)d_out);
}